// Round 17
// baseline (337.623 us; speedup 1.0000x reference)
//
#include <hip/hip_runtime.h>
#include <stdint.h>

// Problem constants
#define B_ 8
#define N_ 4096
#define H_ 8
#define DH_ 64
#define DIM_ 512
#define M_ 266
#define MP_ 320          // padded feature dim
#define BH_ 64
#define BNROWS_ 32768
#define NS_ 8            // ctx n-splits
#define CN_ 0.35355339059327373f      // 64^-0.25
#define RATIO_ 0.06131393394849658f   // 266^-0.5
#define EPS_ 1e-4f
#define REPS_ (RATIO_ * EPS_)

typedef __bf16 bf16x8 __attribute__((ext_vector_type(8)));
typedef float f32x4 __attribute__((ext_vector_type(4)));

union U8 { bf16x8 v; uint4 u; uint2 u2[2]; uint16_t s[8]; };

__device__ __forceinline__ uint32_t f2bf(float f) {
  uint32_t u = __float_as_uint(f);
  u += 0x7FFFu + ((u >> 16) & 1u);   // RNE
  return u >> 16;
}
__device__ __forceinline__ uint32_t pkbf(float a, float b) {
  uint32_t r;
  asm("v_cvt_pk_bf16_f32 %0, %1, %2" : "=v"(r) : "v"(a), "v"(b));
  return r;
}
__device__ __forceinline__ float bflo(uint32_t u) { return __uint_as_float(u << 16); }
__device__ __forceinline__ float bfhi(uint32_t u) { return __uint_as_float(u & 0xFFFF0000u); }
__device__ __forceinline__ void unp8(uint4 u, float* f) {
  f[0] = bflo(u.x); f[1] = bfhi(u.x); f[2] = bflo(u.y); f[3] = bfhi(u.y);
  f[4] = bflo(u.z); f[5] = bfhi(u.z); f[6] = bflo(u.w); f[7] = bfhi(u.w);
}
__device__ __forceinline__ float f4get(const float4& v, int i) {
  return ((const float*)&v)[i];
}
__device__ __forceinline__ uint32_t fenc(float f) {
  uint32_t u = __float_as_uint(f);
  return u ^ ((uint32_t)((int32_t)u >> 31) | 0x80000000u);
}
__device__ __forceinline__ float fdec(uint32_t e) {
  uint32_t u = (e & 0x80000000u) ? (e ^ 0x80000000u) : ~e;
  return __uint_as_float(u);
}
// position-permutation: proj row stored at position p holds original row pi(p)
__device__ __forceinline__ int piperm(int p) {
  int tmt = p >> 4, r = p & 15;
  return 32 * (tmt >> 1) + 8 * (r >> 2) + 4 * (tmt & 1) + (r & 3);
}
// inverse of attn A-frag slot->position map within a 32-window
__device__ __forceinline__ int phinv(int r) {
  int lo = r & 15;
  return 8 * (lo >> 2) + (lo & 3) + ((r >> 4) << 2);
}
// async global->LDS, 16B per lane; lds base must be wave-uniform
__device__ __forceinline__ void glds16(const uint16_t* g, uint16_t* l) {
  __builtin_amdgcn_global_load_lds(
      (const __attribute__((address_space(1))) void*)g,
      (__attribute__((address_space(3))) void*)l, 16, 0, 0);
}

// x fp32 -> bf16, grid-stride (2048 blocks)
__global__ __launch_bounds__(256) void cast_x(const float* __restrict__ x,
                                              uint16_t* __restrict__ xb, int n4) {
  for (int i = blockIdx.x * 256 + threadIdx.x; i < n4; i += 2048 * 256) {
    float4 v = ((const float4*)x)[i];
    uint2 o;
    o.x = f2bf(v.x) | (f2bf(v.y) << 16);
    o.y = f2bf(v.z) | (f2bf(v.w) << 16);
    ((uint2*)xb)[i] = o;
  }
}

// fused weight casts: 4x [512][512] (k,n)->(n,k) bf16 transpose + projb + stab init
__global__ __launch_bounds__(256) void cast_weights(const float* __restrict__ Wq,
                                                    const float* __restrict__ Wk,
                                                    const float* __restrict__ Wv,
                                                    const float* __restrict__ Wo,
                                                    const float* __restrict__ proj,
                                                    uint16_t* __restrict__ wqkvT,
                                                    uint16_t* __restrict__ woT,
                                                    uint16_t* __restrict__ projb,
                                                    uint32_t* __restrict__ stab) {
  int idx = blockIdx.x * 256 + threadIdx.x;
  if (idx < 4 * 262144) {
    int which = idx >> 18, i = idx & 262143;
    const float* src = which == 0 ? Wq : which == 1 ? Wk : which == 2 ? Wv : Wo;
    uint16_t* dst = which < 3 ? wqkvT + (size_t)which * 262144 : woT;
    int k = i >> 9, n = i & 511;
    dst[(size_t)n * 512 + k] = (uint16_t)f2bf(src[i]);
  } else {
    int i = idx - 4 * 262144;
    if (i < MP_ * DH_) {
      int p = i >> 6, d = i & 63;
      int pi = piperm(p);
      float v = (pi < M_) ? proj[pi * DH_ + d] : 0.f;
      projb[i] = (uint16_t)f2bf(v);
    } else if (i == MP_ * DH_) {
      *stab = fenc(-3.4e38f);
    }
  }
}

// ---------------- glds MFMA GEMM (A,B bf16, K=512), 128x128 tile, 512 thr / 8 waves ----
// Wave layout 2x4 (64x32 output per wave), acc 32 AGPR/thread. 2-buffer __syncthreads loop.
// BK=64: 8 barriers + 16B-chunk XOR swizzle (chunk ^= row&7, both-sides: pre-swizzled
// glds SOURCE + swizzled ds_read) -> conflict-free column-slice reads; bit-identical data.
// 1D grid = 8 xcd * 32 bxoff * NBY; concurrent blocks per XCD share one A-tile.
// EPI 0: fp32 C + bias (Ndim 512), direct store. EPI 1: fused QKV (NBY=12) with
// LDS-transpose epilogue (16B coalesced stores for q/k rows and vT rows).
template <int EPI, int NBY, int BK>
__global__ __launch_bounds__(512) void gemm_glds(const uint16_t* __restrict__ A,
                                                 const uint16_t* __restrict__ Bt,
                                                 float* __restrict__ outF,
                                                 const float* __restrict__ bias,
                                                 uint16_t* __restrict__ qb,
                                                 uint16_t* __restrict__ kbuf,
                                                 uint16_t* __restrict__ vTb) {
  constexpr int TILEE = 128 * BK;                       // elems per matrix per buffer
  constexpr int SME = (4 * TILEE > 17408) ? 4 * TILEE : 17408;
  __shared__ __align__(16) uint16_t smem[SME];
  uint16_t (*AsArr)[TILEE] = (uint16_t (*)[TILEE])smem;
  uint16_t (*BsArr)[TILEE] = (uint16_t (*)[TILEE])(smem + 2 * TILEE);
  uint16_t (*epi)[136] = (uint16_t (*)[136])smem;
  const int t = threadIdx.x, lane = t & 63, w = t >> 6;     // w: 0..7
  const int g = lane >> 4, r16 = lane & 15;
  const int wr = (w >> 2) * 64, wc = (w & 3) * 32;          // 2x4 wave grid
  const int flat = blockIdx.x;
  const int xcd = flat & 7, jj = flat >> 3;
  const int bxoff = jj / NBY, by = jj - bxoff * NBY;
  const int bx = xcd * 32 + bxoff;
  const size_t rowA0 = (size_t)bx * 128;
  const size_t rowB0 = (size_t)by * 128;
  const int K = 512;
  constexpr int NK = 512 / BK;

  f32x4 acc[4][2];
#pragma unroll
  for (int i = 0; i < 4; ++i)
#pragma unroll
    for (int j = 0; j < 2; ++j) acc[i][j] = (f32x4){0.f, 0.f, 0.f, 0.f};

  auto stageG = [&](int kt, int buf) {
    if constexpr (BK == 32) {
      const int row0 = w * 16;
      const uint16_t* ga = A + (rowA0 + row0 + (lane >> 2)) * (size_t)K + kt * 32 + (lane & 3) * 8;
      glds16(ga, &AsArr[buf][row0 * 32]);
      const uint16_t* gb = Bt + (rowB0 + row0 + (lane >> 2)) * (size_t)K + kt * 32 + (lane & 3) * 8;
      glds16(gb, &BsArr[buf][row0 * 32]);
    } else {
      // BK=64: 2 glds per matrix; each covers 8 rows (row=lane>>3, chunk=(lane&7)).
      // SOURCE pre-swizzle: chunk ^= (row&7) so linear LDS holds the swizzled layout.
#pragma unroll
      for (int s = 0; s < 2; ++s) {
        const int row0 = w * 16 + s * 8;
        const int r = lane >> 3;                      // row&7 (row0 is 8-aligned)
        const int swz = (lane & 7) ^ r;
        const uint16_t* ga = A + (rowA0 + row0 + r) * (size_t)K + kt * 64 + swz * 8;
        glds16(ga, &AsArr[buf][row0 * 64]);
        const uint16_t* gb = Bt + (rowB0 + row0 + r) * (size_t)K + kt * 64 + swz * 8;
        glds16(gb, &BsArr[buf][row0 * 64]);
      }
    }
  };
  stageG(0, 0);
  for (int kt = 0; kt < NK; ++kt) {
    __syncthreads();    // drains glds (vmcnt) + own ds_reads (lgkmcnt) for prior iter
    if (kt + 1 < NK) stageG(kt + 1, (kt + 1) & 1);
    const uint16_t* as = AsArr[kt & 1];
    const uint16_t* bs = BsArr[kt & 1];
    if constexpr (BK == 32) {
      bf16x8 af[4], bfr[2];
#pragma unroll
      for (int i = 0; i < 4; ++i)
        af[i] = *(const bf16x8*)&as[(wr + i * 16 + r16) * 32 + g * 8];
#pragma unroll
      for (int j = 0; j < 2; ++j)
        bfr[j] = *(const bf16x8*)&bs[(wc + j * 16 + r16) * 32 + g * 8];
#pragma unroll
      for (int i = 0; i < 4; ++i)
#pragma unroll
        for (int j = 0; j < 2; ++j)
          acc[i][j] = __builtin_amdgcn_mfma_f32_16x16x32_bf16(af[i], bfr[j], acc[i][j], 0, 0, 0);
    } else {
      const int rsw = r16 & 7;
#pragma unroll
      for (int kk = 0; kk < 2; ++kk) {
        bf16x8 af[4], bfr[2];
        const int ch = ((kk * 4 + g) ^ rsw) * 8;      // swizzled chunk offset
#pragma unroll
        for (int i = 0; i < 4; ++i)
          af[i] = *(const bf16x8*)&as[(wr + i * 16 + r16) * 64 + ch];
#pragma unroll
        for (int j = 0; j < 2; ++j)
          bfr[j] = *(const bf16x8*)&bs[(wc + j * 16 + r16) * 64 + ch];
#pragma unroll
        for (int i = 0; i < 4; ++i)
#pragma unroll
          for (int j = 0; j < 2; ++j)
            acc[i][j] = __builtin_amdgcn_mfma_f32_16x16x32_bf16(af[i], bfr[j], acc[i][j], 0, 0, 0);
      }
    }
  }
  // epilogue: C-frag row = (lane>>4)*4+reg, col = lane&15
  if constexpr (EPI == 0) {
#pragma unroll
    for (int i = 0; i < 4; ++i) {
      const size_t row0 = rowA0 + wr + i * 16 + g * 4;
#pragma unroll
      for (int j = 0; j < 2; ++j) {
        const size_t col = rowB0 + wc + j * 16 + r16;
        float badd = bias ? bias[col] : 0.f;
#pragma unroll
        for (int q = 0; q < 4; ++q)
          outF[(row0 + q) * (size_t)512 + col] = acc[i][j][q] + badd;
      }
    }
  } else {
    const int region = by >> 2;              // 0=q 1=k 2=v
    const int lcolBase = (by & 3) * 128;
    __syncthreads();                         // staging fully retired; smem becomes epi
    if (region <= 1) {
#pragma unroll
      for (int i = 0; i < 4; ++i)
#pragma unroll
        for (int j = 0; j < 2; ++j)
#pragma unroll
          for (int q = 0; q < 4; ++q)
            epi[wr + i * 16 + g * 4 + q][wc + j * 16 + r16] = (uint16_t)f2bf(acc[i][j][q]);
    } else {
      // deposit transposed: epi[col_local][n_local] so vT rows stream out contiguously
#pragma unroll
      for (int i = 0; i < 4; ++i)
#pragma unroll
        for (int j = 0; j < 2; ++j)
#pragma unroll
          for (int q = 0; q < 4; ++q)
            epi[wc + j * 16 + r16][wr + i * 16 + g * 4 + q] = (uint16_t)f2bf(acc[i][j][q]);
    }
    __syncthreads();
    const int srow = t >> 4, scol = (t & 15) * 8;   // 32 rows x 16 chunks per pass
    if (region <= 1) {
      uint16_t* dst = region ? kbuf : qb;
#pragma unroll
      for (int pass = 0; pass < 4; ++pass) {
        const int row = pass * 32 + srow;
        uint4 v = *(const uint4*)&epi[row][scol];
        *(uint4*)&dst[(rowA0 + row) * (size_t)512 + lcolBase + scol] = v;
      }
    } else {
      const int bb = (int)(rowA0 >> 12), nmod = (int)(rowA0 & 4095);
#pragma unroll
      for (int pass = 0; pass < 4; ++pass) {
        const int erow = pass * 32 + srow;
        const int lcol = lcolBase + erow;
        const int hh = lcol >> 6, e = lcol & 63;
        uint4 v = *(const uint4*)&epi[erow][scol];
        *(uint4*)&vTb[((size_t)((bb * 8 + hh) * 64 + e)) * 4096 + nmod + scol] = v;
      }
    }
  }
}

// ---------------- stab: global max of CN*(k . proj), all 5 m-tiles per staged k ----------------
// grid (bh=64, ns=32), 256 thr (4 waves), 4 n-iters
__global__ __launch_bounds__(256) void stab2_mfma(const uint16_t* __restrict__ kb,
                                                  const uint16_t* __restrict__ projb,
                                                  uint32_t* __restrict__ stab) {
  __shared__ uint16_t kt[2][32][72];
  __shared__ float wred[4];
  const int t = threadIdx.x, lane = t & 63, w = t >> 6;
  const int g = lane >> 4, r16 = lane & 15;
  const int bh = blockIdx.x, ns = blockIdx.y;
  const int b = bh >> 3, h = bh & 7;
  bf16x8 pj[5][2];
  bool mval[5];
#pragma unroll
  for (int mt = 0; mt < 5; ++mt) {
    int m16 = mt * 64 + w * 16;
    pj[mt][0] = *(const bf16x8*)&projb[(m16 + r16) * 64 + g * 8];
    pj[mt][1] = *(const bf16x8*)&projb[(m16 + r16) * 64 + 32 + g * 8];
    mval[mt] = piperm(m16 + r16) < M_;
  }
  auto stage = [&](int it, int buf) {
    int n0 = ns * 128 + it * 32;
    int row = t >> 3, c8 = t & 7;
    *(uint4*)&kt[buf][row][c8 * 8] =
        *(const uint4*)&kb[((size_t)(b * N_ + n0 + row)) * DIM_ + h * DH_ + c8 * 8];
  };
  stage(0, 0);
  __syncthreads();
  float vmax = -3.4e38f;
  for (int it = 0; it < 4; ++it) {
    int cur = it & 1;
    if (it + 1 < 4) stage(it + 1, cur ^ 1);
    bf16x8 ka[2][2];
#pragma unroll
    for (int nsub = 0; nsub < 2; ++nsub) {
      ka[nsub][0] = *(const bf16x8*)&kt[cur][nsub * 16 + r16][g * 8];
      ka[nsub][1] = *(const bf16x8*)&kt[cur][nsub * 16 + r16][32 + g * 8];
    }
#pragma unroll
    for (int mt = 0; mt < 5; ++mt) {
#pragma unroll
      for (int nsub = 0; nsub < 2; ++nsub) {
        f32x4 c4 = (f32x4){0.f, 0.f, 0.f, 0.f};
        c4 = __builtin_amdgcn_mfma_f32_16x16x32_bf16(ka[nsub][0], pj[mt][0], c4, 0, 0, 0);
        c4 = __builtin_amdgcn_mfma_f32_16x16x32_bf16(ka[nsub][1], pj[mt][1], c4, 0, 0, 0);
        if (mval[mt])
          vmax = fmaxf(vmax, fmaxf(fmaxf(c4[0], c4[1]), fmaxf(c4[2], c4[3])));
      }
    }
    __syncthreads();
  }
#pragma unroll
  for (int off = 32; off; off >>= 1) vmax = fmaxf(vmax, __shfl_xor(vmax, off));
  if (lane == 0) wred[w] = vmax;
  __syncthreads();
  if (t == 0) {
    float m = fmaxf(fmaxf(wred[0], wred[1]), fmaxf(wred[2], wred[3]));
    atomicMax(stab, fenc(CN_ * m));
  }
}

// ---------------- ctx: kp-feature + kp^T @ v, MFMA; bf16 partials ----------------
// 1D grid 2560, XCD-sibling mapping: the 5 mt-blocks sharing one (bh,ns) k/vT slice
// get block IDs differing by 8 -> same XCD, back-to-back -> slice stays in that L2.
__global__ __launch_bounds__(256) void ctx_mfma(const uint16_t* __restrict__ kb,
                                                const uint16_t* __restrict__ vTb,
                                                const uint16_t* __restrict__ projb,
                                                const uint32_t* __restrict__ stab_e,
                                                uint16_t* __restrict__ ctxpb,
                                                float* __restrict__ kcump) {
  __shared__ uint16_t kt[2][32][72];
  __shared__ uint16_t vt[2][64][40];
  __shared__ float dk2[2][32];
  __shared__ uint16_t kpb[4][16][40];
  const int t = threadIdx.x, lane = t & 63, w = t >> 6;
  const int g = lane >> 4, r16 = lane & 15;
  const int id = blockIdx.x;
  const int xcd = id & 7, j5 = id >> 3;
  const int mt = j5 % 5, pair = j5 / 5;
  const int bhns = xcd * 64 + pair;
  const int bh = bhns >> 3, ns = bhns & 7;
  const int b = bh >> 3, h = bh & 7;
  const int m16 = mt * 64 + w * 16;
  const float stab = fdec(*stab_e);
  const bool mvalid = piperm(m16 + r16) < M_;
  bf16x8 pj0 = *(const bf16x8*)&projb[(m16 + r16) * 64 + g * 8];
  bf16x8 pj1 = *(const bf16x8*)&projb[(m16 + r16) * 64 + 32 + g * 8];
  const int iters = 4096 / (32 * NS_);

  auto stage = [&](int it, int buf) {
    int n0 = (ns * iters + it) * 32;
    {
      int row = t >> 3, c8 = t & 7;
      uint4 kv = *(const uint4*)&kb[((size_t)(b * N_ + n0 + row)) * DIM_ + h * DH_ + c8 * 8];
      *(uint4*)&kt[buf][row][c8 * 8] = kv;
      float f[8]; unp8(kv, f);
      float sq = f[0]*f[0]+f[1]*f[1]+f[2]*f[2]+f[3]*f[3]+f[4]*f[4]+f[5]*f[5]+f[6]*f[6]+f[7]*f[7];
      sq += __shfl_xor(sq, 1); sq += __shfl_xor(sq, 2); sq += __shfl_xor(sq, 4);
      if (c8 == 0) dk2[buf][row] = 0.5f * CN_ * CN_ * sq;
    }
    {
      int e = t >> 2, c = t & 3;
      uint4 vv = *(const uint4*)&vTb[((size_t)(bh * 64 + e)) * 4096 + n0 + c * 8];
      *(uint4*)&vt[buf][e][c * 8] = vv;
    }
  };
  f32x4 acc[4];
#pragma unroll
  for (int j = 0; j < 4; ++j) acc[j] = (f32x4){0.f, 0.f, 0.f, 0.f};
  float kcacc = 0.f;

  stage(0, 0);
  __syncthreads();
  for (int it = 0; it < iters; ++it) {
    int cur = it & 1;
    if (it + 1 < iters) stage(it + 1, cur ^ 1);
#pragma unroll
    for (int nsub = 0; nsub < 2; ++nsub) {
      bf16x8 ka0 = *(const bf16x8*)&kt[cur][nsub * 16 + r16][g * 8];
      bf16x8 ka1 = *(const bf16x8*)&kt[cur][nsub * 16 + r16][32 + g * 8];
      f32x4 c4 = (f32x4){0.f, 0.f, 0.f, 0.f};
      c4 = __builtin_amdgcn_mfma_f32_16x16x32_bf16(ka0, pj0, c4, 0, 0, 0);
      c4 = __builtin_amdgcn_mfma_f32_16x16x32_bf16(ka1, pj1, c4, 0, 0, 0);
      float4 dkv = *(const float4*)&dk2[cur][nsub * 16 + 4 * g];
      float kp[4];
#pragma unroll
      for (int q = 0; q < 4; ++q) {
        float arg = CN_ * c4[q] - f4get(dkv, q) - stab;
        float e = RATIO_ * __expf(arg) + REPS_;
        kp[q] = mvalid ? e : 0.f;
        kcacc += kp[q];
      }
      *(uint2*)&kpb[w][r16][nsub * 16 + 4 * g] = make_uint2(pkbf(kp[0], kp[1]), pkbf(kp[2], kp[3]));
    }
    U8 kq; kq.u = *(const uint4*)&kpb[w][r16][g * 8];
#pragma unroll
    for (int j = 0; j < 4; ++j) {
      U8 vf; vf.u = *(const uint4*)&vt[cur][j * 16 + r16][g * 8];
      acc[j] = __builtin_amdgcn_mfma_f32_16x16x32_bf16(kq.v, vf.v, acc[j], 0, 0, 0);
    }
    __syncthreads();
  }
  // write ctx^T partials (bf16): lane holds ctx[m16+4g+q][e=j*16+r16]
#pragma unroll
  for (int j = 0; j < 4; ++j) {
    uint2 o;
    o.x = pkbf(acc[j][0], acc[j][1]);
    o.y = pkbf(acc[j][2], acc[j][3]);
    *(uint2*)&ctxpb[(((size_t)ns * BH_ + bh) * 64 + j * 16 + r16) * MP_ + m16 + 4 * g] = o;
  }
  kcacc += __shfl_xor(kcacc, 16);
  kcacc += __shfl_xor(kcacc, 32);
  if (lane < 16) kcump[((size_t)ns * BH_ + bh) * MP_ + m16 + lane] = kcacc;
}

// merge bf16 partials: ctx -> bf16 [bh][e][320] in SLOT order (phinv), kcum -> fp32
__global__ __launch_bounds__(256) void merge_kernel(const uint16_t* __restrict__ ctxpb,
                                                    const float* __restrict__ kcump,
                                                    uint16_t* __restrict__ ctxgb,
                                                    float* __restrict__ kcumg) {
  int idx = blockIdx.x * 256 + threadIdx.x;
  const int total = BH_ * 64 * MP_;
  if (idx < total) {
    float s = 0.f;
#pragma unroll
    for (int p = 0; p < NS_; ++p)
      s += __uint_as_float((uint32_t)ctxpb[(size_t)p * total + idx] << 16);
    int row = idx / MP_;
    int pos = idx - row * MP_;
    int col = (pos & ~31) + phinv(pos & 31);
    ctxgb[(size_t)row * MP_ + col] = (uint16_t)f2bf(s);
  }
  const int ktotal = BH_ * MP_;
  if (idx < ktotal) {
    float s = 0.f;
#pragma unroll
    for (int p = 0; p < NS_; ++p) s += kcump[(size_t)p * ktotal + idx];
    kcumg[idx] = s;
  }
}

// ---------------- attention output: qp feature + qp @ ctx, MFMA ----------------
// 1D grid 512, XCD-sibling mapping (8 nch-blocks per bh -> same XCD L2).
// q loaded DIRECTLY to registers (no LDS stage; dq via shfl over g-groups);
// next iteration's q prefetched during PV. 9 barriers/block (was 16).
__global__ __launch_bounds__(512, 4) void attn_mfma(const uint16_t* __restrict__ qb,
                                                    const uint16_t* __restrict__ projb,
                                                    const uint16_t* __restrict__ ctxgb,
                                                    const float* __restrict__ kcumg,
                                                    uint16_t* __restrict__ attnb) {
  __shared__ uint16_t ctile[64][328];
  __shared__ uint16_t outb[128][72];
  __shared__ float kcums[MP_];
  __shared__ float denb[8][16];
  const int t = threadIdx.x, lane = t & 63, w = t >> 6;
  const int g = lane >> 4, r16 = lane & 15;
  const int id = blockIdx.x;
  const int xcd = id & 7, j8 = id >> 3;
  const int bh = xcd * 8 + (j8 >> 3);
  const int nch = j8 & 7;
  const int b = bh >> 3, h = bh & 7;
  {
    int row = t >> 3, cb = t & 7;
#pragma unroll
    for (int cc = 0; cc < 5; ++cc) {
      int cN = cb * 40 + cc * 8;
      *(uint4*)&ctile[row][cN] = *(const uint4*)&ctxgb[((size_t)bh * 64 + row) * MP_ + cN];
    }
  }
  if (t < MP_) kcums[t] = kcumg[(size_t)bh * MP_ + t];
  // preload iter-0 q fragment for this lane (row = nbase + w*16 + r16)
  const uint16_t* qrow0 =
      qb + ((size_t)(b * N_ + nch * 512 + w * 16 + r16)) * DIM_ + h * DH_;
  uint4 qa = *(const uint4*)(qrow0 + g * 8);
  uint4 qc = *(const uint4*)(qrow0 + 32 + g * 8);
  __syncthreads();   // ctile + kcums staged

  for (int it = 0; it < 4; ++it) {
    const int nbase = nch * 512 + it * 128;
    // dq for this row: lane partial (16 elems) + shfl over g-groups
    float fq[8];
    float sq;
    {
      unp8(qa, fq);
      sq = fq[0]*fq[0]+fq[1]*fq[1]+fq[2]*fq[2]+fq[3]*fq[3]+fq[4]*fq[4]+fq[5]*fq[5]+fq[6]*fq[6]+fq[7]*fq[7];
      unp8(qc, fq);
      sq += fq[0]*fq[0]+fq[1]*fq[1]+fq[2]*fq[2]+fq[3]*fq[3]+fq[4]*fq[4]+fq[5]*fq[5]+fq[6]*fq[6]+fq[7]*fq[7];
      sq += __shfl_xor(sq, 16);
      sq += __shfl_xor(sq, 32);
    }
    const float dqrow = 0.5f * CN_ * CN_ * sq;
    U8 q0, q1; q0.u = qa; q1.u = qc;
    // prefetch next iteration's q (overlaps with S/softmax/PV below)
    if (it + 1 < 4) {
      const uint16_t* qn =
          qb + ((size_t)(b * N_ + nbase + 128 + w * 16 + r16)) * DIM_ + h * DH_;
      qa = *(const uint4*)(qn + g * 8);
      qc = *(const uint4*)(qn + 32 + g * 8);
    }
    f32x4 S[18];
#pragma unroll
    for (int mt = 0; mt < 18; ++mt) {
      bf16x8 pa0 = *(const bf16x8*)&projb[(mt * 16 + r16) * 64 + g * 8];
      bf16x8 pa1 = *(const bf16x8*)&projb[(mt * 16 + r16) * 64 + 32 + g * 8];
      f32x4 c4 = (f32x4){0.f, 0.f, 0.f, 0.f};
      c4 = __builtin_amdgcn_mfma_f32_16x16x32_bf16(pa0, q0.v, c4, 0, 0, 0);
      S[mt] = __builtin_amdgcn_mfma_f32_16x16x32_bf16(pa1, q1.v, c4, 0, 0, 0);
    }
    float rmax = -3.4e38f;
#pragma unroll
    for (int mt = 0; mt < 18; ++mt) {
#pragma unroll
      for (int q = 0; q < 4; ++q) {
        bool val = (mt < 16) || (256 + 4 * (mt & 1) + 8 * g + q < M_);
        if (val) rmax = fmaxf(rmax, CN_ * S[mt][q]);
      }
    }
    rmax = fmaxf(rmax, __shfl_xor(rmax, 16));
    rmax = fmaxf(rmax, __shfl_xor(rmax, 32));
    const float offv = rmax + dqrow;
    float denp = 0.f;
    uint32_t pk[18][2];
#pragma unroll
    for (int mt = 0; mt < 18; ++mt) {
      float4 kc4 = *(const float4*)&kcums[mt * 16 + 4 * g];
      float qp[4];
#pragma unroll
      for (int q = 0; q < 4; ++q) {
        bool val = (mt < 16) || (256 + 4 * (mt & 1) + 8 * g + q < M_);
        float e = RATIO_ * __expf(CN_ * S[mt][q] - offv) + REPS_;
        qp[q] = val ? e : 0.f;
        denp += qp[q] * f4get(kc4, q);
      }
      pk[mt][0] = pkbf(qp[0], qp[1]);
      pk[mt][1] = pkbf(qp[2], qp[3]);
    }
    denp += __shfl_xor(denp, 16);
    denp += __shfl_xor(denp, 32);
    if (lane < 16) denb[w][lane] = denp;
    f32x4 o[4];
#pragma unroll
    for (int j = 0; j < 4; ++j) o[j] = (f32x4){0.f, 0.f, 0.f, 0.f};
#pragma unroll
    for (int s = 0; s < 9; ++s) {
      U8 af; af.u = make_uint4(pk[2 * s][0], pk[2 * s][1], pk[2 * s + 1][0], pk[2 * s + 1][1]);
#pragma unroll
      for (int j = 0; j < 4; ++j) {
        U8 cf; cf.u = *(const uint4*)&ctile[j * 16 + r16][s * 32 + g * 8];
        o[j] = __builtin_amdgcn_mfma_f32_16x16x32_bf16(af.v, cf.v, o[j], 0, 0, 0);
      }
    }
    float4 dv = *(const float4*)&denb[w][4 * g];
    float rd[4];
#pragma unroll
    for (int q = 0; q < 4; ++q) rd[q] = 1.0f / f4get(dv, q);
    // coalesced output: deposit out[n_local][e] (wave-private rows), stream 128B rows
    __syncthreads();   // prior iter's store reads of outb complete (WAR)
#pragma unroll
    for (int j = 0; j < 4; ++j)
#pragma unroll
      for (int q = 0; q < 4; ++q)
        outb[w * 16 + 4 * g + q][j * 16 + r16] = (uint16_t)f2bf(o[j][q] * rd[q]);
    __syncthreads();
    {
      const int srow = t >> 3, scol = (t & 7) * 8;
#pragma unroll
      for (int pass = 0; pass < 2; ++pass) {
        const int row = pass * 64 + srow;
        uint4 v = *(const uint4*)&outb[row][scol];
        *(uint4*)&attnb[((size_t)(b * N_ + nbase + row)) * DIM_ + h * DH_ + scol] = v;
      }
    }
  }
}

extern "C" void kernel_launch(void* const* d_in, const int* in_sizes, int n_in,
                              void* d_out, int out_size, void* d_ws, size_t ws_size,
                              hipStream_t stream) {
  const float* x = (const float*)d_in[0];
  const float* Wq = (const float*)d_in[1];
  const float* Wk = (const float*)d_in[2];
  const float* Wv = (const float*)d_in[3];
  const float* Wo = (const float*)d_in[4];
  const float* bo = (const float*)d_in[5];
  const float* proj = (const float*)d_in[6];
  float* out = (float*)d_out;

  char* ws = (char*)d_ws;
  size_t off = 0;
  auto alloc = [&](size_t bytes) {
    char* p = ws + off;
    off += (bytes + 255) & ~(size_t)255;
    return p;
  };
  // ws total ~93.7 MB (ws_size >= 95MB proven in R5)
  uint16_t* wqkvT = (uint16_t*)alloc((size_t)1536 * 512 * 2);   // rows: q cols, k cols, v cols
  uint16_t* woT = (uint16_t*)alloc((size_t)512 * 512 * 2);
  uint16_t* projb = (uint16_t*)alloc((size_t)MP_ * DH_ * 2);
  uint16_t* vTb = (uint16_t*)alloc((size_t)BNROWS_ * DIM_ * 2);  // vT, later attnb
  uint16_t* ctxpb = (uint16_t*)alloc((size_t)NS_ * BH_ * 64 * MP_ * 2);
  float* kcump = (float*)alloc((size_t)NS_ * BH_ * MP_ * 4);
  uint16_t* ctxgb = (uint16_t*)alloc((size_t)BH_ * 64 * MP_ * 2);
  float* kcumg = (float*)alloc((size_t)BH_ * MP_ * 4);
  uint32_t* stab = (uint32_t*)alloc(256);
  uint16_t* xb = (uint16_t*)alloc((size_t)BNROWS_ * DIM_ * 2);
  // q,k staged in d_out (fully overwritten by the final GEMM afterwards)
  uint16_t* qb = (uint16_t*)d_out;
  uint16_t* kb = qb + (size_t)BNROWS_ * DIM_;
  uint16_t* attnb = vTb;

  cast_weights<<<4177, 256, 0, stream>>>(Wq, Wk, Wv, Wo, proj, wqkvT, woT, projb, stab);
  cast_x<<<2048, 256, 0, stream>>>(x, xb, BNROWS_ * DIM_ / 4);

  gemm_glds<1, 12, 64><<<3072, 512, 0, stream>>>(xb, wqkvT, nullptr, nullptr, qb, kb, vTb);

  stab2_mfma<<<dim3(64, 32), 256, 0, stream>>>(kb, projb, stab);
  ctx_mfma<<<2560, 256, 0, stream>>>(kb, vTb, projb, stab, ctxpb, kcump);
  merge_kernel<<<5120, 256, 0, stream>>>(ctxpb, kcump, ctxgb, kcumg);
  attn_mfma<<<512, 512, 0, stream>>>(qb, projb, ctxgb, kcumg, attnb);
  gemm_glds<0, 4, 64><<<1024, 512, 0, stream>>>(attnb, woT, out, bo, nullptr, nullptr, nullptr);
}

// Round 18
// 257.855 us; speedup vs baseline: 1.3094x; 1.3094x over previous
//
#include <hip/hip_runtime.h>
#include <stdint.h>

// Problem constants
#define B_ 8
#define N_ 4096
#define H_ 8
#define DH_ 64
#define DIM_ 512
#define M_ 266
#define MP_ 320          // padded feature dim
#define BH_ 64
#define BNROWS_ 32768
#define NS_ 8            // ctx n-splits
#define CN_ 0.35355339059327373f      // 64^-0.25
#define RATIO_ 0.06131393394849658f   // 266^-0.5
#define EPS_ 1e-4f
#define REPS_ (RATIO_ * EPS_)

typedef __bf16 bf16x8 __attribute__((ext_vector_type(8)));
typedef float f32x4 __attribute__((ext_vector_type(4)));

union U8 { bf16x8 v; uint4 u; uint2 u2[2]; uint16_t s[8]; };

__device__ __forceinline__ uint32_t f2bf(float f) {
  uint32_t u = __float_as_uint(f);
  u += 0x7FFFu + ((u >> 16) & 1u);   // RNE
  return u >> 16;
}
__device__ __forceinline__ uint32_t pkbf(float a, float b) {
  uint32_t r;
  asm("v_cvt_pk_bf16_f32 %0, %1, %2" : "=v"(r) : "v"(a), "v"(b));
  return r;
}
__device__ __forceinline__ float bflo(uint32_t u) { return __uint_as_float(u << 16); }
__device__ __forceinline__ float bfhi(uint32_t u) { return __uint_as_float(u & 0xFFFF0000u); }
__device__ __forceinline__ void unp8(uint4 u, float* f) {
  f[0] = bflo(u.x); f[1] = bfhi(u.x); f[2] = bflo(u.y); f[3] = bfhi(u.y);
  f[4] = bflo(u.z); f[5] = bfhi(u.z); f[6] = bflo(u.w); f[7] = bfhi(u.w);
}
__device__ __forceinline__ float f4get(const float4& v, int i) {
  return ((const float*)&v)[i];
}
__device__ __forceinline__ uint32_t fenc(float f) {
  uint32_t u = __float_as_uint(f);
  return u ^ ((uint32_t)((int32_t)u >> 31) | 0x80000000u);
}
__device__ __forceinline__ float fdec(uint32_t e) {
  uint32_t u = (e & 0x80000000u) ? (e ^ 0x80000000u) : ~e;
  return __uint_as_float(u);
}
// position-permutation: proj row stored at position p holds original row pi(p)
__device__ __forceinline__ int piperm(int p) {
  int tmt = p >> 4, r = p & 15;
  return 32 * (tmt >> 1) + 8 * (r >> 2) + 4 * (tmt & 1) + (r & 3);
}
// inverse of attn A-frag slot->position map within a 32-window
__device__ __forceinline__ int phinv(int r) {
  int lo = r & 15;
  return 8 * (lo >> 2) + (lo & 3) + ((r >> 4) << 2);
}
// async global->LDS, 16B per lane; lds base must be wave-uniform
__device__ __forceinline__ void glds16(const uint16_t* g, uint16_t* l) {
  __builtin_amdgcn_global_load_lds(
      (const __attribute__((address_space(1))) void*)g,
      (__attribute__((address_space(3))) void*)l, 16, 0, 0);
}

// x fp32 -> bf16, grid-stride (2048 blocks)
__global__ __launch_bounds__(256) void cast_x(const float* __restrict__ x,
                                              uint16_t* __restrict__ xb, int n4) {
  for (int i = blockIdx.x * 256 + threadIdx.x; i < n4; i += 2048 * 256) {
    float4 v = ((const float4*)x)[i];
    uint2 o;
    o.x = f2bf(v.x) | (f2bf(v.y) << 16);
    o.y = f2bf(v.z) | (f2bf(v.w) << 16);
    ((uint2*)xb)[i] = o;
  }
}

// fused weight casts: 4x [512][512] (k,n)->(n,k) bf16 transpose + projb + stab init
__global__ __launch_bounds__(256) void cast_weights(const float* __restrict__ Wq,
                                                    const float* __restrict__ Wk,
                                                    const float* __restrict__ Wv,
                                                    const float* __restrict__ Wo,
                                                    const float* __restrict__ proj,
                                                    uint16_t* __restrict__ wqkvT,
                                                    uint16_t* __restrict__ woT,
                                                    uint16_t* __restrict__ projb,
                                                    uint32_t* __restrict__ stab) {
  int idx = blockIdx.x * 256 + threadIdx.x;
  if (idx < 4 * 262144) {
    int which = idx >> 18, i = idx & 262143;
    const float* src = which == 0 ? Wq : which == 1 ? Wk : which == 2 ? Wv : Wo;
    uint16_t* dst = which < 3 ? wqkvT + (size_t)which * 262144 : woT;
    int k = i >> 9, n = i & 511;
    dst[(size_t)n * 512 + k] = (uint16_t)f2bf(src[i]);
  } else {
    int i = idx - 4 * 262144;
    if (i < MP_ * DH_) {
      int p = i >> 6, d = i & 63;
      int pi = piperm(p);
      float v = (pi < M_) ? proj[pi * DH_ + d] : 0.f;
      projb[i] = (uint16_t)f2bf(v);
    } else if (i == MP_ * DH_) {
      *stab = fenc(-3.4e38f);
    }
  }
}

// ---------------- glds MFMA GEMM (A,B bf16, K=512), 128x128 tile, 512 thr / 8 waves ----
// Wave layout 2x4 (64x32 output per wave), acc 32 AGPR/thread. 2-buffer __syncthreads loop.
// BK=64: 8 barriers + 16B-chunk XOR swizzle (chunk ^= row&7, both-sides: pre-swizzled
// glds SOURCE + swizzled ds_read) -> conflict-free column-slice reads; bit-identical data.
// 1D grid = 8 xcd * 32 bxoff * NBY; concurrent blocks per XCD share one A-tile.
// EPI 0: fp32 C + bias (Ndim 512), direct store. EPI 1: fused QKV (NBY=12) with
// LDS-transpose epilogue (16B coalesced stores for q/k rows and vT rows).
template <int EPI, int NBY, int BK>
__global__ __launch_bounds__(512) void gemm_glds(const uint16_t* __restrict__ A,
                                                 const uint16_t* __restrict__ Bt,
                                                 float* __restrict__ outF,
                                                 const float* __restrict__ bias,
                                                 uint16_t* __restrict__ qb,
                                                 uint16_t* __restrict__ kbuf,
                                                 uint16_t* __restrict__ vTb) {
  constexpr int TILEE = 128 * BK;                       // elems per matrix per buffer
  constexpr int SME = (4 * TILEE > 17408) ? 4 * TILEE : 17408;
  __shared__ __align__(16) uint16_t smem[SME];
  uint16_t (*AsArr)[TILEE] = (uint16_t (*)[TILEE])smem;
  uint16_t (*BsArr)[TILEE] = (uint16_t (*)[TILEE])(smem + 2 * TILEE);
  uint16_t (*epi)[136] = (uint16_t (*)[136])smem;
  const int t = threadIdx.x, lane = t & 63, w = t >> 6;     // w: 0..7
  const int g = lane >> 4, r16 = lane & 15;
  const int wr = (w >> 2) * 64, wc = (w & 3) * 32;          // 2x4 wave grid
  const int flat = blockIdx.x;
  const int xcd = flat & 7, jj = flat >> 3;
  const int bxoff = jj / NBY, by = jj - bxoff * NBY;
  const int bx = xcd * 32 + bxoff;
  const size_t rowA0 = (size_t)bx * 128;
  const size_t rowB0 = (size_t)by * 128;
  const int K = 512;
  constexpr int NK = 512 / BK;

  f32x4 acc[4][2];
#pragma unroll
  for (int i = 0; i < 4; ++i)
#pragma unroll
    for (int j = 0; j < 2; ++j) acc[i][j] = (f32x4){0.f, 0.f, 0.f, 0.f};

  auto stageG = [&](int kt, int buf) {
    if constexpr (BK == 32) {
      const int row0 = w * 16;
      const uint16_t* ga = A + (rowA0 + row0 + (lane >> 2)) * (size_t)K + kt * 32 + (lane & 3) * 8;
      glds16(ga, &AsArr[buf][row0 * 32]);
      const uint16_t* gb = Bt + (rowB0 + row0 + (lane >> 2)) * (size_t)K + kt * 32 + (lane & 3) * 8;
      glds16(gb, &BsArr[buf][row0 * 32]);
    } else {
      // BK=64: 2 glds per matrix; each covers 8 rows (row=lane>>3, chunk=(lane&7)).
      // SOURCE pre-swizzle: chunk ^= (row&7) so linear LDS holds the swizzled layout.
#pragma unroll
      for (int s = 0; s < 2; ++s) {
        const int row0 = w * 16 + s * 8;
        const int r = lane >> 3;                      // row&7 (row0 is 8-aligned)
        const int swz = (lane & 7) ^ r;
        const uint16_t* ga = A + (rowA0 + row0 + r) * (size_t)K + kt * 64 + swz * 8;
        glds16(ga, &AsArr[buf][row0 * 64]);
        const uint16_t* gb = Bt + (rowB0 + row0 + r) * (size_t)K + kt * 64 + swz * 8;
        glds16(gb, &BsArr[buf][row0 * 64]);
      }
    }
  };
  stageG(0, 0);
  for (int kt = 0; kt < NK; ++kt) {
    __syncthreads();    // drains glds (vmcnt) + own ds_reads (lgkmcnt) for prior iter
    if (kt + 1 < NK) stageG(kt + 1, (kt + 1) & 1);
    const uint16_t* as = AsArr[kt & 1];
    const uint16_t* bs = BsArr[kt & 1];
    if constexpr (BK == 32) {
      bf16x8 af[4], bfr[2];
#pragma unroll
      for (int i = 0; i < 4; ++i)
        af[i] = *(const bf16x8*)&as[(wr + i * 16 + r16) * 32 + g * 8];
#pragma unroll
      for (int j = 0; j < 2; ++j)
        bfr[j] = *(const bf16x8*)&bs[(wc + j * 16 + r16) * 32 + g * 8];
#pragma unroll
      for (int i = 0; i < 4; ++i)
#pragma unroll
        for (int j = 0; j < 2; ++j)
          acc[i][j] = __builtin_amdgcn_mfma_f32_16x16x32_bf16(af[i], bfr[j], acc[i][j], 0, 0, 0);
    } else {
      const int rsw = r16 & 7;
#pragma unroll
      for (int kk = 0; kk < 2; ++kk) {
        bf16x8 af[4], bfr[2];
        const int ch = ((kk * 4 + g) ^ rsw) * 8;      // swizzled chunk offset
#pragma unroll
        for (int i = 0; i < 4; ++i)
          af[i] = *(const bf16x8*)&as[(wr + i * 16 + r16) * 64 + ch];
#pragma unroll
        for (int j = 0; j < 2; ++j)
          bfr[j] = *(const bf16x8*)&bs[(wc + j * 16 + r16) * 64 + ch];
#pragma unroll
        for (int i = 0; i < 4; ++i)
#pragma unroll
          for (int j = 0; j < 2; ++j)
            acc[i][j] = __builtin_amdgcn_mfma_f32_16x16x32_bf16(af[i], bfr[j], acc[i][j], 0, 0, 0);
      }
    }
  }
  // epilogue: C-frag row = (lane>>4)*4+reg, col = lane&15
  if constexpr (EPI == 0) {
#pragma unroll
    for (int i = 0; i < 4; ++i) {
      const size_t row0 = rowA0 + wr + i * 16 + g * 4;
#pragma unroll
      for (int j = 0; j < 2; ++j) {
        const size_t col = rowB0 + wc + j * 16 + r16;
        float badd = bias ? bias[col] : 0.f;
#pragma unroll
        for (int q = 0; q < 4; ++q)
          outF[(row0 + q) * (size_t)512 + col] = acc[i][j][q] + badd;
      }
    }
  } else {
    const int region = by >> 2;              // 0=q 1=k 2=v
    const int lcolBase = (by & 3) * 128;
    __syncthreads();                         // staging fully retired; smem becomes epi
    if (region <= 1) {
#pragma unroll
      for (int i = 0; i < 4; ++i)
#pragma unroll
        for (int j = 0; j < 2; ++j)
#pragma unroll
          for (int q = 0; q < 4; ++q)
            epi[wr + i * 16 + g * 4 + q][wc + j * 16 + r16] = (uint16_t)f2bf(acc[i][j][q]);
    } else {
      // deposit transposed: epi[col_local][n_local] so vT rows stream out contiguously
#pragma unroll
      for (int i = 0; i < 4; ++i)
#pragma unroll
        for (int j = 0; j < 2; ++j)
#pragma unroll
          for (int q = 0; q < 4; ++q)
            epi[wc + j * 16 + r16][wr + i * 16 + g * 4 + q] = (uint16_t)f2bf(acc[i][j][q]);
    }
    __syncthreads();
    const int srow = t >> 4, scol = (t & 15) * 8;   // 32 rows x 16 chunks per pass
    if (region <= 1) {
      uint16_t* dst = region ? kbuf : qb;
#pragma unroll
      for (int pass = 0; pass < 4; ++pass) {
        const int row = pass * 32 + srow;
        uint4 v = *(const uint4*)&epi[row][scol];
        *(uint4*)&dst[(rowA0 + row) * (size_t)512 + lcolBase + scol] = v;
      }
    } else {
      const int bb = (int)(rowA0 >> 12), nmod = (int)(rowA0 & 4095);
#pragma unroll
      for (int pass = 0; pass < 4; ++pass) {
        const int erow = pass * 32 + srow;
        const int lcol = lcolBase + erow;
        const int hh = lcol >> 6, e = lcol & 63;
        uint4 v = *(const uint4*)&epi[erow][scol];
        *(uint4*)&vTb[((size_t)((bb * 8 + hh) * 64 + e)) * 4096 + nmod + scol] = v;
      }
    }
  }
}

// ---------------- stab: global max of CN*(k . proj), all 5 m-tiles per staged k ----------------
// grid (bh=64, ns=32), 256 thr (4 waves), 4 n-iters
__global__ __launch_bounds__(256) void stab2_mfma(const uint16_t* __restrict__ kb,
                                                  const uint16_t* __restrict__ projb,
                                                  uint32_t* __restrict__ stab) {
  __shared__ uint16_t kt[2][32][72];
  __shared__ float wred[4];
  const int t = threadIdx.x, lane = t & 63, w = t >> 6;
  const int g = lane >> 4, r16 = lane & 15;
  const int bh = blockIdx.x, ns = blockIdx.y;
  const int b = bh >> 3, h = bh & 7;
  bf16x8 pj[5][2];
  bool mval[5];
#pragma unroll
  for (int mt = 0; mt < 5; ++mt) {
    int m16 = mt * 64 + w * 16;
    pj[mt][0] = *(const bf16x8*)&projb[(m16 + r16) * 64 + g * 8];
    pj[mt][1] = *(const bf16x8*)&projb[(m16 + r16) * 64 + 32 + g * 8];
    mval[mt] = piperm(m16 + r16) < M_;
  }
  auto stage = [&](int it, int buf) {
    int n0 = ns * 128 + it * 32;
    int row = t >> 3, c8 = t & 7;
    *(uint4*)&kt[buf][row][c8 * 8] =
        *(const uint4*)&kb[((size_t)(b * N_ + n0 + row)) * DIM_ + h * DH_ + c8 * 8];
  };
  stage(0, 0);
  __syncthreads();
  float vmax = -3.4e38f;
  for (int it = 0; it < 4; ++it) {
    int cur = it & 1;
    if (it + 1 < 4) stage(it + 1, cur ^ 1);
    bf16x8 ka[2][2];
#pragma unroll
    for (int nsub = 0; nsub < 2; ++nsub) {
      ka[nsub][0] = *(const bf16x8*)&kt[cur][nsub * 16 + r16][g * 8];
      ka[nsub][1] = *(const bf16x8*)&kt[cur][nsub * 16 + r16][32 + g * 8];
    }
#pragma unroll
    for (int mt = 0; mt < 5; ++mt) {
#pragma unroll
      for (int nsub = 0; nsub < 2; ++nsub) {
        f32x4 c4 = (f32x4){0.f, 0.f, 0.f, 0.f};
        c4 = __builtin_amdgcn_mfma_f32_16x16x32_bf16(ka[nsub][0], pj[mt][0], c4, 0, 0, 0);
        c4 = __builtin_amdgcn_mfma_f32_16x16x32_bf16(ka[nsub][1], pj[mt][1], c4, 0, 0, 0);
        if (mval[mt])
          vmax = fmaxf(vmax, fmaxf(fmaxf(c4[0], c4[1]), fmaxf(c4[2], c4[3])));
      }
    }
    __syncthreads();
  }
#pragma unroll
  for (int off = 32; off; off >>= 1) vmax = fmaxf(vmax, __shfl_xor(vmax, off));
  if (lane == 0) wred[w] = vmax;
  __syncthreads();
  if (t == 0) {
    float m = fmaxf(fmaxf(wred[0], wred[1]), fmaxf(wred[2], wred[3]));
    atomicMax(stab, fenc(CN_ * m));
  }
}

// ---------------- ctx: kp-feature + kp^T @ v, MFMA; bf16 partials ----------------
// 1D grid 2560, XCD-sibling mapping: the 5 mt-blocks sharing one (bh,ns) k/vT slice
// get block IDs differing by 8 -> same XCD, back-to-back -> slice stays in that L2.
__global__ __launch_bounds__(256) void ctx_mfma(const uint16_t* __restrict__ kb,
                                                const uint16_t* __restrict__ vTb,
                                                const uint16_t* __restrict__ projb,
                                                const uint32_t* __restrict__ stab_e,
                                                uint16_t* __restrict__ ctxpb,
                                                float* __restrict__ kcump) {
  __shared__ uint16_t kt[2][32][72];
  __shared__ uint16_t vt[2][64][40];
  __shared__ float dk2[2][32];
  __shared__ uint16_t kpb[4][16][40];
  const int t = threadIdx.x, lane = t & 63, w = t >> 6;
  const int g = lane >> 4, r16 = lane & 15;
  const int id = blockIdx.x;
  const int xcd = id & 7, j5 = id >> 3;
  const int mt = j5 % 5, pair = j5 / 5;
  const int bhns = xcd * 64 + pair;
  const int bh = bhns >> 3, ns = bhns & 7;
  const int b = bh >> 3, h = bh & 7;
  const int m16 = mt * 64 + w * 16;
  const float stab = fdec(*stab_e);
  const bool mvalid = piperm(m16 + r16) < M_;
  bf16x8 pj0 = *(const bf16x8*)&projb[(m16 + r16) * 64 + g * 8];
  bf16x8 pj1 = *(const bf16x8*)&projb[(m16 + r16) * 64 + 32 + g * 8];
  const int iters = 4096 / (32 * NS_);

  auto stage = [&](int it, int buf) {
    int n0 = (ns * iters + it) * 32;
    {
      int row = t >> 3, c8 = t & 7;
      uint4 kv = *(const uint4*)&kb[((size_t)(b * N_ + n0 + row)) * DIM_ + h * DH_ + c8 * 8];
      *(uint4*)&kt[buf][row][c8 * 8] = kv;
      float f[8]; unp8(kv, f);
      float sq = f[0]*f[0]+f[1]*f[1]+f[2]*f[2]+f[3]*f[3]+f[4]*f[4]+f[5]*f[5]+f[6]*f[6]+f[7]*f[7];
      sq += __shfl_xor(sq, 1); sq += __shfl_xor(sq, 2); sq += __shfl_xor(sq, 4);
      if (c8 == 0) dk2[buf][row] = 0.5f * CN_ * CN_ * sq;
    }
    {
      int e = t >> 2, c = t & 3;
      uint4 vv = *(const uint4*)&vTb[((size_t)(bh * 64 + e)) * 4096 + n0 + c * 8];
      *(uint4*)&vt[buf][e][c * 8] = vv;
    }
  };
  f32x4 acc[4];
#pragma unroll
  for (int j = 0; j < 4; ++j) acc[j] = (f32x4){0.f, 0.f, 0.f, 0.f};
  float kcacc = 0.f;

  stage(0, 0);
  __syncthreads();
  for (int it = 0; it < iters; ++it) {
    int cur = it & 1;
    if (it + 1 < iters) stage(it + 1, cur ^ 1);
#pragma unroll
    for (int nsub = 0; nsub < 2; ++nsub) {
      bf16x8 ka0 = *(const bf16x8*)&kt[cur][nsub * 16 + r16][g * 8];
      bf16x8 ka1 = *(const bf16x8*)&kt[cur][nsub * 16 + r16][32 + g * 8];
      f32x4 c4 = (f32x4){0.f, 0.f, 0.f, 0.f};
      c4 = __builtin_amdgcn_mfma_f32_16x16x32_bf16(ka0, pj0, c4, 0, 0, 0);
      c4 = __builtin_amdgcn_mfma_f32_16x16x32_bf16(ka1, pj1, c4, 0, 0, 0);
      float4 dkv = *(const float4*)&dk2[cur][nsub * 16 + 4 * g];
      float kp[4];
#pragma unroll
      for (int q = 0; q < 4; ++q) {
        float arg = CN_ * c4[q] - f4get(dkv, q) - stab;
        float e = RATIO_ * __expf(arg) + REPS_;
        kp[q] = mvalid ? e : 0.f;
        kcacc += kp[q];
      }
      *(uint2*)&kpb[w][r16][nsub * 16 + 4 * g] = make_uint2(pkbf(kp[0], kp[1]), pkbf(kp[2], kp[3]));
    }
    U8 kq; kq.u = *(const uint4*)&kpb[w][r16][g * 8];
#pragma unroll
    for (int j = 0; j < 4; ++j) {
      U8 vf; vf.u = *(const uint4*)&vt[cur][j * 16 + r16][g * 8];
      acc[j] = __builtin_amdgcn_mfma_f32_16x16x32_bf16(kq.v, vf.v, acc[j], 0, 0, 0);
    }
    __syncthreads();
  }
  // write ctx^T partials (bf16): lane holds ctx[m16+4g+q][e=j*16+r16]
#pragma unroll
  for (int j = 0; j < 4; ++j) {
    uint2 o;
    o.x = pkbf(acc[j][0], acc[j][1]);
    o.y = pkbf(acc[j][2], acc[j][3]);
    *(uint2*)&ctxpb[(((size_t)ns * BH_ + bh) * 64 + j * 16 + r16) * MP_ + m16 + 4 * g] = o;
  }
  kcacc += __shfl_xor(kcacc, 16);
  kcacc += __shfl_xor(kcacc, 32);
  if (lane < 16) kcump[((size_t)ns * BH_ + bh) * MP_ + m16 + lane] = kcacc;
}

// merge bf16 partials: ctx -> bf16 [bh][e][320] in SLOT order (phinv), kcum -> fp32
__global__ __launch_bounds__(256) void merge_kernel(const uint16_t* __restrict__ ctxpb,
                                                    const float* __restrict__ kcump,
                                                    uint16_t* __restrict__ ctxgb,
                                                    float* __restrict__ kcumg) {
  int idx = blockIdx.x * 256 + threadIdx.x;
  const int total = BH_ * 64 * MP_;
  if (idx < total) {
    float s = 0.f;
#pragma unroll
    for (int p = 0; p < NS_; ++p)
      s += __uint_as_float((uint32_t)ctxpb[(size_t)p * total + idx] << 16);
    int row = idx / MP_;
    int pos = idx - row * MP_;
    int col = (pos & ~31) + phinv(pos & 31);
    ctxgb[(size_t)row * MP_ + col] = (uint16_t)f2bf(s);
  }
  const int ktotal = BH_ * MP_;
  if (idx < ktotal) {
    float s = 0.f;
#pragma unroll
    for (int p = 0; p < NS_; ++p) s += kcump[(size_t)p * ktotal + idx];
    kcumg[idx] = s;
  }
}

// ---------------- attention output: qp feature + qp @ ctx, MFMA ----------------
// 1D grid 512, XCD-sibling mapping: the 8 nch-blocks sharing one bh's ctx/kcum get
// block IDs differing by 8 -> same XCD -> ctx stays in that L2 after first fetch.
// 512 thr (8 waves); output staged through qs for coalesced stores. (R16 proven form)
__global__ __launch_bounds__(512) void attn_mfma(const uint16_t* __restrict__ qb,
                                                 const uint16_t* __restrict__ projb,
                                                 const uint16_t* __restrict__ ctxgb,
                                                 const float* __restrict__ kcumg,
                                                 uint16_t* __restrict__ attnb) {
  __shared__ uint16_t ctile[64][328];
  __shared__ uint16_t qs[128][72];
  __shared__ float kcums[MP_];
  __shared__ float dqs[128];
  __shared__ float denb[8][16];
  const int t = threadIdx.x, lane = t & 63, w = t >> 6;
  const int g = lane >> 4, r16 = lane & 15;
  const int id = blockIdx.x;
  const int xcd = id & 7, j8 = id >> 3;
  const int bh = xcd * 8 + (j8 >> 3);
  const int nch = j8 & 7;
  const int b = bh >> 3, h = bh & 7;
  {
    int row = t >> 3, cb = t & 7;
#pragma unroll
    for (int cc = 0; cc < 5; ++cc) {
      int cN = cb * 40 + cc * 8;
      *(uint4*)&ctile[row][cN] = *(const uint4*)&ctxgb[((size_t)bh * 64 + row) * MP_ + cN];
    }
  }
  if (t < MP_) kcums[t] = kcumg[(size_t)bh * MP_ + t];

  for (int it = 0; it < 4; ++it) {
    const int nbase = nch * 512 + it * 128;
    __syncthreads();
    {
      int row = t >> 2, c2 = t & 3;
      float sq = 0.f;
#pragma unroll
      for (int cc = 0; cc < 2; ++cc) {
        int c8 = c2 * 2 + cc;
        uint4 qv = *(const uint4*)&qb[((size_t)(b * N_ + nbase + row)) * DIM_ + h * DH_ + c8 * 8];
        *(uint4*)&qs[row][c8 * 8] = qv;
        float f[8]; unp8(qv, f);
        sq += f[0]*f[0]+f[1]*f[1]+f[2]*f[2]+f[3]*f[3]+f[4]*f[4]+f[5]*f[5]+f[6]*f[6]+f[7]*f[7];
      }
      sq += __shfl_xor(sq, 1); sq += __shfl_xor(sq, 2);
      if (c2 == 0) dqs[row] = 0.5f * CN_ * CN_ * sq;
    }
    __syncthreads();
    bf16x8 qf0 = *(const bf16x8*)&qs[w * 16 + r16][g * 8];
    bf16x8 qf1 = *(const bf16x8*)&qs[w * 16 + r16][32 + g * 8];
    f32x4 S[18];
#pragma unroll
    for (int mt = 0; mt < 18; ++mt) {
      bf16x8 pa0 = *(const bf16x8*)&projb[(mt * 16 + r16) * 64 + g * 8];
      bf16x8 pa1 = *(const bf16x8*)&projb[(mt * 16 + r16) * 64 + 32 + g * 8];
      f32x4 c4 = (f32x4){0.f, 0.f, 0.f, 0.f};
      c4 = __builtin_amdgcn_mfma_f32_16x16x32_bf16(pa0, qf0, c4, 0, 0, 0);
      S[mt] = __builtin_amdgcn_mfma_f32_16x16x32_bf16(pa1, qf1, c4, 0, 0, 0);
    }
    float rmax = -3.4e38f;
#pragma unroll
    for (int mt = 0; mt < 18; ++mt) {
#pragma unroll
      for (int q = 0; q < 4; ++q) {
        bool val = (mt < 16) || (256 + 4 * (mt & 1) + 8 * g + q < M_);
        if (val) rmax = fmaxf(rmax, CN_ * S[mt][q]);
      }
    }
    rmax = fmaxf(rmax, __shfl_xor(rmax, 16));
    rmax = fmaxf(rmax, __shfl_xor(rmax, 32));
    const float offv = rmax + dqs[w * 16 + r16];
    float denp = 0.f;
    uint32_t pk[18][2];
#pragma unroll
    for (int mt = 0; mt < 18; ++mt) {
      float4 kc4 = *(const float4*)&kcums[mt * 16 + 4 * g];
      float qp[4];
#pragma unroll
      for (int q = 0; q < 4; ++q) {
        bool val = (mt < 16) || (256 + 4 * (mt & 1) + 8 * g + q < M_);
        float e = RATIO_ * __expf(CN_ * S[mt][q] - offv) + REPS_;
        qp[q] = val ? e : 0.f;
        denp += qp[q] * f4get(kc4, q);
      }
      pk[mt][0] = pkbf(qp[0], qp[1]);
      pk[mt][1] = pkbf(qp[2], qp[3]);
    }
    denp += __shfl_xor(denp, 16);
    denp += __shfl_xor(denp, 32);
    if (lane < 16) denb[w][lane] = denp;
    f32x4 o[4];
#pragma unroll
    for (int j = 0; j < 4; ++j) o[j] = (f32x4){0.f, 0.f, 0.f, 0.f};
#pragma unroll
    for (int s = 0; s < 9; ++s) {
      U8 af; af.u = make_uint4(pk[2 * s][0], pk[2 * s][1], pk[2 * s + 1][0], pk[2 * s + 1][1]);
#pragma unroll
      for (int j = 0; j < 4; ++j) {
        U8 cf; cf.u = *(const uint4*)&ctile[j * 16 + r16][s * 32 + g * 8];
        o[j] = __builtin_amdgcn_mfma_f32_16x16x32_bf16(af.v, cf.v, o[j], 0, 0, 0);
      }
    }
    float4 dv = *(const float4*)&denb[w][4 * g];
    float rd[4];
#pragma unroll
    for (int q = 0; q < 4; ++q) rd[q] = 1.0f / f4get(dv, q);
    // coalesced output via qs reuse: deposit out[n_local][e], then stream 128B rows
    __syncthreads();   // all waves done reading qs (q-frags live in registers)
#pragma unroll
    for (int j = 0; j < 4; ++j)
#pragma unroll
      for (int q = 0; q < 4; ++q)
        qs[w * 16 + 4 * g + q][j * 16 + r16] = (uint16_t)f2bf(o[j][q] * rd[q]);
    __syncthreads();
    {
      const int srow = t >> 3, scol = (t & 7) * 8;
#pragma unroll
      for (int pass = 0; pass < 2; ++pass) {
        const int row = pass * 64 + srow;
        uint4 v = *(const uint4*)&qs[row][scol];
        *(uint4*)&attnb[((size_t)(b * N_ + nbase + row)) * DIM_ + h * DH_ + scol] = v;
      }
    }
  }
}

extern "C" void kernel_launch(void* const* d_in, const int* in_sizes, int n_in,
                              void* d_out, int out_size, void* d_ws, size_t ws_size,
                              hipStream_t stream) {
  const float* x = (const float*)d_in[0];
  const float* Wq = (const float*)d_in[1];
  const float* Wk = (const float*)d_in[2];
  const float* Wv = (const float*)d_in[3];
  const float* Wo = (const float*)d_in[4];
  const float* bo = (const float*)d_in[5];
  const float* proj = (const float*)d_in[6];
  float* out = (float*)d_out;

  char* ws = (char*)d_ws;
  size_t off = 0;
  auto alloc = [&](size_t bytes) {
    char* p = ws + off;
    off += (bytes + 255) & ~(size_t)255;
    return p;
  };
  // ws total ~93.7 MB (ws_size >= 95MB proven in R5)
  uint16_t* wqkvT = (uint16_t*)alloc((size_t)1536 * 512 * 2);   // rows: q cols, k cols, v cols
  uint16_t* woT = (uint16_t*)alloc((size_t)512 * 512 * 2);
  uint16_t* projb = (uint16_t*)alloc((size_t)MP_ * DH_ * 2);
  uint16_t* vTb = (uint16_t*)alloc((size_t)BNROWS_ * DIM_ * 2);  // vT, later attnb
  uint16_t* ctxpb = (uint16_t*)alloc((size_t)NS_ * BH_ * 64 * MP_ * 2);
  float* kcump = (float*)alloc((size_t)NS_ * BH_ * MP_ * 4);
  uint16_t* ctxgb = (uint16_t*)alloc((size_t)BH_ * 64 * MP_ * 2);
  float* kcumg = (float*)alloc((size_t)BH_ * MP_ * 4);
  uint32_t* stab = (uint32_t*)alloc(256);
  uint16_t* xb = (uint16_t*)alloc((size_t)BNROWS_ * DIM_ * 2);
  // q,k staged in d_out (fully overwritten by the final GEMM afterwards)
  uint16_t* qb = (uint16_t*)d_out;
  uint16_t* kb = qb + (size_t)BNROWS_ * DIM_;
  uint16_t* attnb = vTb;

  cast_weights<<<4177, 256, 0, stream>>>(Wq, Wk, Wv, Wo, proj, wqkvT, woT, projb, stab);
  cast_x<<<2048, 256, 0, stream>>>(x, xb, BNROWS_ * DIM_ / 4);

  gemm_glds<1, 12, 64><<<3072, 512, 0, stream>>>(xb, wqkvT, nullptr, nullptr, qb, kb, vTb);

  stab2_mfma<<<dim3(64, 32), 256, 0, stream>>>(kb, projb, stab);
  ctx_mfma<<<2560, 256, 0, stream>>>(kb, vTb, projb, stab, ctxpb, kcump);
  merge_kernel<<<5120, 256, 0, stream>>>(ctxpb, kcump, ctxgb, kcumg);
  attn_mfma<<<512, 512, 0, stream>>>(qb, projb, ctxgb, kcumg, attnb);
  gemm_glds<0, 4, 64><<<1024, 512, 0, stream>>>(attnb, woT, out, bo, nullptr, nullptr, nullptr);
}